// Round 1
// baseline (480.160 us; speedup 1.0000x reference)
//
#include <hip/hip_runtime.h>
#include <hip/hip_bf16.h>
#include <math.h>

typedef __bf16 bf16x8 __attribute__((ext_vector_type(8)));
typedef float floatx4 __attribute__((ext_vector_type(4)));

#define ATT_SCALE 0.35355339059327373f  // DH^-0.5, DH=8

__device__ __forceinline__ __bf16 f2b(float x) { return (__bf16)x; }

#define FMA8(A, X, WP) do {                                    \
    const float4 _wa = *(const float4*)(WP);                   \
    const float4 _wb = *(const float4*)((WP) + 4);             \
    A[0] += (X) * _wa.x; A[1] += (X) * _wa.y;                  \
    A[2] += (X) * _wa.z; A[3] += (X) * _wa.w;                  \
    A[4] += (X) * _wb.x; A[5] += (X) * _wb.y;                  \
    A[6] += (X) * _wb.z; A[7] += (X) * _wb.w;                  \
  } while (0)

// ---------------------------------------------------------------------------
// K1: Q = p@wq, Ks = (p@wk)*SCALE, V = p@wv  (rows 0..2047), q1 = queries@cq_wq
// grid 2304 x 64
// ---------------------------------------------------------------------------
__global__ void k_proj(const float* __restrict__ p, const float* __restrict__ quer,
                       const float* __restrict__ wq, const float* __restrict__ wk,
                       const float* __restrict__ wv, const float* __restrict__ cq_wq,
                       float* __restrict__ Q, float* __restrict__ Ks,
                       float* __restrict__ V, float* __restrict__ q1) {
  int blk = blockIdx.x, t = threadIdx.x;
  __shared__ float xr[64];
  if (blk < 2048) {
    xr[t] = p[blk * 64 + t];
    __syncthreads();
    float aq = 0.f, ak = 0.f, av = 0.f;
    for (int c = 0; c < 64; c++) {
      float x = xr[c];
      aq += x * wq[c * 64 + t];
      ak += x * wk[c * 64 + t];
      av += x * wv[c * 64 + t];
    }
    Q[blk * 64 + t] = aq;
    Ks[blk * 64 + t] = ak * ATT_SCALE;
    V[blk * 64 + t] = av;
  } else {
    int r = blk - 2048;  // 0..255 query rows
    xr[t] = quer[r * 64 + t];
    __syncthreads();
    float a = 0.f;
    for (int c = 0; c < 64; c++) a += xr[c] * cq_wq[c * 64 + t];
    q1[r * 64 + t] = a;
  }
}

// ---------------------------------------------------------------------------
// K2 v2: edge attention with TRANSPOSED MFMA: acc = mfma(wfrag, efrag) gives
// E^T tiles (row = hk, col = j). A lane's 4 acc values are 4 consecutive hk
// of the SAME head-half -> k-reduction is 4 in-lane FMAs + one shfl_xor(16).
// exp redundancy 8x -> 2x; Ks/Q/V become float4 loads.
// grid 2048 x 256 (wave w owns j in [w*64, w*64+64))
// ---------------------------------------------------------------------------
__global__ __launch_bounds__(256) void k_edge(
    const float* __restrict__ e, const float* __restrict__ we,
    const float* __restrict__ krw, const float* __restrict__ mask,
    const float* __restrict__ hin, const float* __restrict__ pin,
    const float* __restrict__ wo, const float* __restrict__ cq_wkv,
    const float* __restrict__ Q, const float* __restrict__ Ks,
    const float* __restrict__ V, float* __restrict__ Kc, float* __restrict__ Vc) {
  int bi = blockIdx.x;          // b*256 + i
  int b = bi >> 8;
  int t = threadIdx.x;
  int w = t >> 6, l = t & 63;
  int l15 = l & 15, quad = l >> 4;
  int hsel = quad >> 1;         // head offset within an nt pair (0 or 1)

  // we fragments: lane holds we[c = kc*32+quad*8+jj][hk = nt*16+l15]
  // (same fragment as before; used as the MFMA *A* operand now -> E^T)
  bf16x8 wfrag[4][2];
  for (int nt = 0; nt < 4; nt++)
    for (int kc = 0; kc < 2; kc++)
      for (int jj = 0; jj < 8; jj++)
        wfrag[nt][kc][jj] = f2b(we[(kc * 32 + quad * 8 + jj) * 64 + nt * 16 + l15]);

  // Q fragments: qv[nt] = Q[i][nt*16 + quad*4 .. +3]
  float4 qv[4];
#pragma unroll
  for (int nt = 0; nt < 4; nt++)
    qv[nt] = *(const float4*)(Q + bi * 64 + nt * 16 + quad * 4);

  float mi = mask[bi];

  float aout[4][8];
  float aden[4] = {0.f, 0.f, 0.f, 0.f};
#pragma unroll
  for (int nt = 0; nt < 4; nt++)
#pragma unroll
    for (int d = 0; d < 8; d++) aout[nt][d] = 0.f;

  for (int jt = 0; jt < 4; jt++) {
    int j0 = w * 64 + jt * 16;
    int j = j0 + l15;           // this lane's column of the E^T tile
    // e fragment (B-operand): B[k=quad*8+jj][n=l15] = e[j][kc*32+quad*8+jj]
    const float* ep = e + ((long)bi * 256 + j) * 64 + quad * 8;
    float4 ea = *reinterpret_cast<const float4*>(ep);
    float4 eb4 = *reinterpret_cast<const float4*>(ep + 4);
    float4 ec = *reinterpret_cast<const float4*>(ep + 32);
    float4 ed4 = *reinterpret_cast<const float4*>(ep + 36);
    bf16x8 a0, a1;
    a0[0] = f2b(ea.x); a0[1] = f2b(ea.y); a0[2] = f2b(ea.z); a0[3] = f2b(ea.w);
    a0[4] = f2b(eb4.x); a0[5] = f2b(eb4.y); a0[6] = f2b(eb4.z); a0[7] = f2b(eb4.w);
    a1[0] = f2b(ec.x); a1[1] = f2b(ec.y); a1[2] = f2b(ec.z); a1[3] = f2b(ec.w);
    a1[4] = f2b(ed4.x); a1[5] = f2b(ed4.y); a1[6] = f2b(ed4.z); a1[7] = f2b(ed4.w);

    float kwm = krw[(long)bi * 256 + j] * mask[b * 256 + j];
    const float* ksrow = Ks + ((long)(b * 256 + j)) * 64 + quad * 4;
    const float* vrow0 = V + ((long)(b * 256 + j)) * 64 + hsel * 8;

#pragma unroll
    for (int nt = 0; nt < 4; nt++) {
      floatx4 acc = {0.f, 0.f, 0.f, 0.f};
      acc = __builtin_amdgcn_mfma_f32_16x16x32_bf16(wfrag[nt][0], a0, acc, 0, 0, 0);
      acc = __builtin_amdgcn_mfma_f32_16x16x32_bf16(wfrag[nt][1], a1, acc, 0, 0, 0);
      // acc[r] = E[hk = nt*16 + quad*4 + r][j]
      float4 kf = *(const float4*)(ksrow + nt * 16);
      float s = acc[0] * kf.x * qv[nt].x + acc[1] * kf.y * qv[nt].y +
                acc[2] * kf.z * qv[nt].z + acc[3] * kf.w * qv[nt].w;
      s += __shfl_xor(s, 16);   // combine quad pairs {0,1},{2,3}: full 8-k head sum
      float wg = __expf(s) * kwm;
      aden[nt] += wg;
      const float4 va = *(const float4*)(vrow0 + nt * 16);
      const float4 vb = *(const float4*)(vrow0 + nt * 16 + 4);
      aout[nt][0] += wg * va.x; aout[nt][1] += wg * va.y;
      aout[nt][2] += wg * va.z; aout[nt][3] += wg * va.w;
      aout[nt][4] += wg * vb.x; aout[nt][5] += wg * vb.y;
      aout[nt][6] += wg * vb.z; aout[nt][7] += wg * vb.w;
    }
  }

  // reduce over the 16 j's per lane-group (l15); quad pairs hold duplicates
#pragma unroll
  for (int nt = 0; nt < 4; nt++) {
    float dn = aden[nt];
    dn += __shfl_xor(dn, 1); dn += __shfl_xor(dn, 2);
    dn += __shfl_xor(dn, 4); dn += __shfl_xor(dn, 8);
    aden[nt] = dn;
#pragma unroll
    for (int d = 0; d < 8; d++) {
      float o = aout[nt][d];
      o += __shfl_xor(o, 1); o += __shfl_xor(o, 2);
      o += __shfl_xor(o, 4); o += __shfl_xor(o, 8);
      aout[nt][d] = o;
    }
  }

  __shared__ float red[4][64];
  __shared__ float redden[4][8];
  __shared__ float pav[64];
  __shared__ float hcl[64];
  if (l15 == 0 && (quad & 1) == 0) {   // lanes 0 and 32 per wave
#pragma unroll
    for (int nt = 0; nt < 4; nt++) {
      int head = nt * 2 + hsel;
#pragma unroll
      for (int d = 0; d < 8; d++) red[w][head * 8 + d] = aout[nt][d];
      redden[w][head] = aden[nt];
    }
  }
  __syncthreads();
  if (t < 64) {
    int head = t >> 3;
    float num = red[0][t] + red[1][t] + red[2][t] + red[3][t];
    float den = redden[0][head] + redden[1][head] + redden[2][head] + redden[3][head];
    num *= mi;
    den = fmaxf(den * mi, 1e-6f);
    pav[t] = num / den;  // p_attn[b,i,head*8+d]
  }
  __syncthreads();
  if (t < 64) {
    float a = 0.f;
    for (int c = 0; c < 64; c++) a += pav[c] * wo[c * 64 + t];
    hcl[t] = hin[bi * 64 + t] + pin[bi * 64 + t] + tanhf(a);
  }
  __syncthreads();
  if (t < 128) {
    float a = 0.f;
    for (int c = 0; c < 64; c++) a += hcl[c] * cq_wkv[c * 128 + t];
    if (t < 64) Kc[bi * 64 + t] = a;
    else        Vc[bi * 64 + t - 64] = a;
  }
}

// ---------------------------------------------------------------------------
// K3: fused tail — cross-attn + 2 latent self-attn blocks + out proj + LN/FFN.
// One block per batch b (grid 8 x 256); all intermediates live in LDS.
//   phase maps: attention phases use (h = t>>5, r = t&31);
//               matmul phases use (r2 = t>>3, c0 = (t&7)*8).
// ---------------------------------------------------------------------------
__global__ __launch_bounds__(256) void k_tail(
    const float* __restrict__ q1, const float* __restrict__ Kc,
    const float* __restrict__ Vc, const float* __restrict__ mask,
    const float* __restrict__ quer,
    const float* __restrict__ cq_wo, const float* __restrict__ cq_bo,
    const float* __restrict__ sa_wq, const float* __restrict__ sa_wkv,
    const float* __restrict__ sa_wo, const float* __restrict__ sa_bo,
    const float* __restrict__ oq_w, const float* __restrict__ ln1g,
    const float* __restrict__ ln1b, const float* __restrict__ w1,
    const float* __restrict__ w2, const float* __restrict__ ln2g,
    const float* __restrict__ ln2b, float* __restrict__ out) {
  int b = blockIdx.x, t = threadIdx.x;
  __shared__ float KT[32][64];   // K tiles / self-attn K / FFN hidden lo
  __shared__ float VT[32][64];   // V tiles / self-attn V / FFN hidden hi
  __shared__ float msk[256];
  __shared__ float ocs[32][64];  // attn outputs (cross, then self)
  __shared__ float q0s[32][64];  // q0, later LN1 output y
  __shared__ float qqs[32][64];  // qq, later q2
  __shared__ float qc1s[32][64];

  msk[t] = mask[b * 256 + t];

  int h = t >> 5, r = t & 31;
  int r2 = t >> 3, c0 = (t & 7) * 8;

  // ---- phase 1: perceiver cross-attention (latents attend to 256 nodes) ----
  {
    const float* qp = q1 + (b * 32 + r) * 64 + h * 8;
    float4 qa = *(const float4*)qp;
    float4 qb = *(const float4*)(qp + 4);
    float num[8] = {0.f, 0.f, 0.f, 0.f, 0.f, 0.f, 0.f, 0.f};
    float den = 0.f;
    for (int jt = 0; jt < 8; jt++) {
      __syncthreads();
      const float* ksrc = Kc + (b * 256 + jt * 32) * 64 + t * 8;
      const float* vsrc = Vc + (b * 256 + jt * 32) * 64 + t * 8;
      float4 k0 = *(const float4*)ksrc, k1 = *(const float4*)(ksrc + 4);
      float4 v0 = *(const float4*)vsrc, v1 = *(const float4*)(vsrc + 4);
      int rr = t >> 3, cc = (t & 7) * 8;
      *(float4*)&KT[rr][cc] = k0; *(float4*)&KT[rr][cc + 4] = k1;
      *(float4*)&VT[rr][cc] = v0; *(float4*)&VT[rr][cc + 4] = v1;
      __syncthreads();
      for (int jj = 0; jj < 32; jj++) {
        float4 ka = *(const float4*)&KT[jj][h * 8];
        float4 kb = *(const float4*)&KT[jj][h * 8 + 4];
        float s = qa.x * ka.x + qa.y * ka.y + qa.z * ka.z + qa.w * ka.w +
                  qb.x * kb.x + qb.y * kb.y + qb.z * kb.z + qb.w * kb.w;
        s *= ATT_SCALE;
        float mj = msk[jt * 32 + jj];
        s = (mj > 0.5f) ? s : -1e30f;
        s = fminf(fmaxf(s, -5.f), 5.f);
        float ex = __expf(s);
        den += ex;
        float4 va = *(const float4*)&VT[jj][h * 8];
        float4 vb = *(const float4*)&VT[jj][h * 8 + 4];
        num[0] += ex * va.x; num[1] += ex * va.y;
        num[2] += ex * va.z; num[3] += ex * va.w;
        num[4] += ex * vb.x; num[5] += ex * vb.y;
        num[6] += ex * vb.z; num[7] += ex * vb.w;
      }
    }
    float inv = 1.f / den;
#pragma unroll
    for (int d = 0; d < 8; d++) ocs[r][h * 8 + d] = num[d] * inv;
  }
  __syncthreads();

  // ---- phase 2a: q0 = queries + oc@cq_wo + cq_bo ----
  {
    float acc[8];
    const float* rp = quer + (b * 32 + r2) * 64 + c0;
#pragma unroll
    for (int o = 0; o < 8; o++) acc[o] = rp[o] + cq_bo[c0 + o];
    const float* xr = &ocs[r2][0];
    for (int c = 0; c < 64; c++) FMA8(acc, xr[c], cq_wo + c * 64 + c0);
#pragma unroll
    for (int o = 0; o < 8; o++) q0s[r2][c0 + o] = acc[o];
  }
  __syncthreads();

  // ---- phase 2b: qq = q0@sa_wq[0]; K,V = q0@sa_wkv[0] ----
  {
    float aq[8] = {0.f, 0.f, 0.f, 0.f, 0.f, 0.f, 0.f, 0.f};
    float ak[8] = {0.f, 0.f, 0.f, 0.f, 0.f, 0.f, 0.f, 0.f};
    float av[8] = {0.f, 0.f, 0.f, 0.f, 0.f, 0.f, 0.f, 0.f};
    const float* xr = &q0s[r2][0];
    for (int c = 0; c < 64; c++) {
      float x = xr[c];
      FMA8(aq, x, sa_wq + c * 64 + c0);
      FMA8(ak, x, sa_wkv + c * 128 + c0);
      FMA8(av, x, sa_wkv + c * 128 + 64 + c0);
    }
#pragma unroll
    for (int o = 0; o < 8; o++) {
      qqs[r2][c0 + o] = aq[o];
      KT[r2][c0 + o] = ak[o];
      VT[r2][c0 + o] = av[o];
    }
  }
  __syncthreads();

#define SATTN(QSRC)                                                          \
  {                                                                          \
    const float* qpp = &QSRC[r][h * 8];                                      \
    float4 sqa = *(const float4*)qpp;                                        \
    float4 sqb = *(const float4*)(qpp + 4);                                  \
    float nm[8] = {0.f, 0.f, 0.f, 0.f, 0.f, 0.f, 0.f, 0.f};                  \
    float dn = 0.f;                                                          \
    for (int j = 0; j < 32; j++) {                                           \
      float4 ka = *(const float4*)&KT[j][h * 8];                             \
      float4 kb = *(const float4*)&KT[j][h * 8 + 4];                         \
      float s = sqa.x * ka.x + sqa.y * ka.y + sqa.z * ka.z + sqa.w * ka.w +  \
                sqb.x * kb.x + sqb.y * kb.y + sqb.z * kb.z + sqb.w * kb.w;   \
      s *= ATT_SCALE;                                                        \
      s = fminf(fmaxf(s, -5.f), 5.f);                                        \
      float ex = __expf(s);                                                  \
      dn += ex;                                                              \
      float4 va = *(const float4*)&VT[j][h * 8];                             \
      float4 vb = *(const float4*)&VT[j][h * 8 + 4];                         \
      nm[0] += ex * va.x; nm[1] += ex * va.y;                                \
      nm[2] += ex * va.z; nm[3] += ex * va.w;                                \
      nm[4] += ex * vb.x; nm[5] += ex * vb.y;                                \
      nm[6] += ex * vb.z; nm[7] += ex * vb.w;                                \
    }                                                                        \
    float inv = 1.f / dn;                                                    \
    _Pragma("unroll")                                                        \
    for (int d = 0; d < 8; d++) ocs[r][h * 8 + d] = nm[d] * inv;             \
  }

  // ---- phase 3: latent self-attention layer 0 ----
  SATTN(qqs);
  __syncthreads();

  // ---- phase 4a: qc1 = q0 + os@sa_wo[0] + sa_bo[0] ----
  {
    float acc[8];
#pragma unroll
    for (int o = 0; o < 8; o++) acc[o] = q0s[r2][c0 + o] + sa_bo[c0 + o];
    const float* xr = &ocs[r2][0];
    for (int c = 0; c < 64; c++) FMA8(acc, xr[c], sa_wo + c * 64 + c0);
#pragma unroll
    for (int o = 0; o < 8; o++) qc1s[r2][c0 + o] = acc[o];
  }
  __syncthreads();

  // ---- phase 4b: qq = qc1@sa_wq[1]; K,V = qc1@sa_wkv[1] ----
  {
    float aq[8] = {0.f, 0.f, 0.f, 0.f, 0.f, 0.f, 0.f, 0.f};
    float ak[8] = {0.f, 0.f, 0.f, 0.f, 0.f, 0.f, 0.f, 0.f};
    float av[8] = {0.f, 0.f, 0.f, 0.f, 0.f, 0.f, 0.f, 0.f};
    const float* xr = &qc1s[r2][0];
    const float* wqL = sa_wq + 4096;
    const float* wkvL = sa_wkv + 8192;
    for (int c = 0; c < 64; c++) {
      float x = xr[c];
      FMA8(aq, x, wqL + c * 64 + c0);
      FMA8(ak, x, wkvL + c * 128 + c0);
      FMA8(av, x, wkvL + c * 128 + 64 + c0);
    }
#pragma unroll
    for (int o = 0; o < 8; o++) {
      qqs[r2][c0 + o] = aq[o];
      KT[r2][c0 + o] = ak[o];
      VT[r2][c0 + o] = av[o];
    }
  }
  __syncthreads();

  // ---- phase 5: latent self-attention layer 1 ----
  SATTN(qqs);
  __syncthreads();

  // ---- phase 6a: q2 = qc1 + os@sa_wo[1] + sa_bo[1]  (store into qqs) ----
  {
    float acc[8];
#pragma unroll
    for (int o = 0; o < 8; o++) acc[o] = qc1s[r2][c0 + o] + sa_bo[64 + c0 + o];
    const float* xr = &ocs[r2][0];
    const float* woL = sa_wo + 4096;
    for (int c = 0; c < 64; c++) FMA8(acc, xr[c], woL + c * 64 + c0);
#pragma unroll
    for (int o = 0; o < 8; o++) qqs[r2][c0 + o] = acc[o];
  }
  __syncthreads();

  // ---- phase 6b: x = q2@oq_w ; LN1 -> y (regs + q0s) ----
  float yv[8];
  {
    float acc[8] = {0.f, 0.f, 0.f, 0.f, 0.f, 0.f, 0.f, 0.f};
    const float* xr = &qqs[r2][0];
    for (int c = 0; c < 64; c++) FMA8(acc, xr[c], oq_w + c * 64 + c0);
    float sm = acc[0] + acc[1] + acc[2] + acc[3] + acc[4] + acc[5] + acc[6] + acc[7];
    sm += __shfl_xor(sm, 1); sm += __shfl_xor(sm, 2); sm += __shfl_xor(sm, 4);
    float mean = sm * 0.015625f;
    float vs = 0.f;
#pragma unroll
    for (int o = 0; o < 8; o++) { float d = acc[o] - mean; vs += d * d; }
    vs += __shfl_xor(vs, 1); vs += __shfl_xor(vs, 2); vs += __shfl_xor(vs, 4);
    float rstd = rsqrtf(vs * 0.015625f + 1e-5f);
#pragma unroll
    for (int o = 0; o < 8; o++) {
      yv[o] = (acc[o] - mean) * rstd * ln1g[c0 + o] + ln1b[c0 + o];
      q0s[r2][c0 + o] = yv[o];
    }
  }
  __syncthreads();

  // ---- phase 6c: hidden = relu(y@w1), 128 wide -> KT|VT ----
  {
    int c1 = (t & 7) * 16;
    float ah[16];
#pragma unroll
    for (int o = 0; o < 16; o++) ah[o] = 0.f;
    const float* xr = &q0s[r2][0];
    for (int c = 0; c < 64; c++) {
      float x = xr[c];
      const float* wp = &w1[c * 128 + c1];
      float4 wa = *(const float4*)wp;
      float4 wb = *(const float4*)(wp + 4);
      float4 wc = *(const float4*)(wp + 8);
      float4 wd = *(const float4*)(wp + 12);
      ah[0] += x * wa.x;  ah[1] += x * wa.y;  ah[2] += x * wa.z;  ah[3] += x * wa.w;
      ah[4] += x * wb.x;  ah[5] += x * wb.y;  ah[6] += x * wb.z;  ah[7] += x * wb.w;
      ah[8] += x * wc.x;  ah[9] += x * wc.y;  ah[10] += x * wc.z; ah[11] += x * wc.w;
      ah[12] += x * wd.x; ah[13] += x * wd.y; ah[14] += x * wd.z; ah[15] += x * wd.w;
    }
    if (c1 < 64) {
#pragma unroll
      for (int o = 0; o < 16; o++) KT[r2][c1 + o] = fmaxf(ah[o], 0.f);
    } else {
#pragma unroll
      for (int o = 0; o < 16; o++) VT[r2][c1 - 64 + o] = fmaxf(ah[o], 0.f);
    }
  }
  __syncthreads();

  // ---- phase 6d: ff = hidden@w2 ; z = y + ff ; LN2 -> out ----
  {
    float ff[8] = {0.f, 0.f, 0.f, 0.f, 0.f, 0.f, 0.f, 0.f};
    for (int c = 0; c < 64; c++) FMA8(ff, KT[r2][c], w2 + c * 64 + c0);
    for (int c = 0; c < 64; c++) FMA8(ff, VT[r2][c], w2 + (c + 64) * 64 + c0);
    float z[8];
#pragma unroll
    for (int o = 0; o < 8; o++) z[o] = yv[o] + ff[o];
    float sm = z[0] + z[1] + z[2] + z[3] + z[4] + z[5] + z[6] + z[7];
    sm += __shfl_xor(sm, 1); sm += __shfl_xor(sm, 2); sm += __shfl_xor(sm, 4);
    float mean = sm * 0.015625f;
    float vs = 0.f;
#pragma unroll
    for (int o = 0; o < 8; o++) { float d = z[o] - mean; vs += d * d; }
    vs += __shfl_xor(vs, 1); vs += __shfl_xor(vs, 2); vs += __shfl_xor(vs, 4);
    float rstd = rsqrtf(vs * 0.015625f + 1e-5f);
    float* op = out + (b * 32 + r2) * 64 + c0;
#pragma unroll
    for (int o = 0; o < 8; o++)
      op[o] = (z[o] - mean) * rstd * ln2g[c0 + o] + ln2b[c0 + o];
  }
}

// ---------------------------------------------------------------------------
extern "C" void kernel_launch(void* const* d_in, const int* in_sizes, int n_in,
                              void* d_out, int out_size, void* d_ws, size_t ws_size,
                              hipStream_t stream) {
  const float* h_in   = (const float*)d_in[0];
  const float* p_in   = (const float*)d_in[1];
  const float* e_in   = (const float*)d_in[2];
  const float* krw    = (const float*)d_in[3];
  const float* quer   = (const float*)d_in[4];
  const float* mask   = (const float*)d_in[5];
  const float* wq_p   = (const float*)d_in[6];
  const float* wk_p   = (const float*)d_in[7];
  const float* we_p   = (const float*)d_in[8];
  const float* wv_p   = (const float*)d_in[9];
  const float* wo_p   = (const float*)d_in[10];
  const float* cq_wq  = (const float*)d_in[11];
  const float* cq_wkv = (const float*)d_in[12];
  const float* cq_wo  = (const float*)d_in[13];
  const float* cq_bo  = (const float*)d_in[14];
  const float* sa_wq  = (const float*)d_in[15];
  const float* sa_wkv = (const float*)d_in[16];
  const float* sa_wo  = (const float*)d_in[17];
  const float* sa_bo  = (const float*)d_in[18];
  const float* oq_w   = (const float*)d_in[19];
  const float* ln1_g  = (const float*)d_in[20];
  const float* ln1_b  = (const float*)d_in[21];
  const float* ffn_w1 = (const float*)d_in[22];
  const float* ffn_w2 = (const float*)d_in[23];
  const float* ln2_g  = (const float*)d_in[24];
  const float* ln2_b  = (const float*)d_in[25];

  float* ws = (float*)d_ws;
  float* Q   = ws;              // 131072
  float* Ks  = Q + 131072;      // 131072
  float* V   = Ks + 131072;     // 131072
  float* q1  = V + 131072;      // 16384
  float* Kc  = q1 + 16384;      // 131072
  float* Vc  = Kc + 131072;     // 131072

  k_proj<<<2304, 64, 0, stream>>>(p_in, quer, wq_p, wk_p, wv_p, cq_wq, Q, Ks, V, q1);
  k_edge<<<2048, 256, 0, stream>>>(e_in, we_p, krw, mask, h_in, p_in, wo_p, cq_wkv,
                                   Q, Ks, V, Kc, Vc);
  k_tail<<<8, 256, 0, stream>>>(q1, Kc, Vc, mask, quer, cq_wo, cq_bo,
                                sa_wq, sa_wkv, sa_wo, sa_bo, oq_w,
                                ln1_g, ln1_b, ffn_w1, ffn_w2, ln2_g, ln2_b,
                                (float*)d_out);
}

// Round 2
// 322.128 us; speedup vs baseline: 1.4906x; 1.4906x over previous
//
#include <hip/hip_runtime.h>
#include <hip/hip_bf16.h>
#include <math.h>

typedef __bf16 bf16x8 __attribute__((ext_vector_type(8)));
typedef float floatx4 __attribute__((ext_vector_type(4)));

#define ATT_SCALE 0.35355339059327373f  // DH^-0.5, DH=8

__device__ __forceinline__ __bf16 f2b(float x) { return (__bf16)x; }

// ---------------------------------------------------------------------------
// K1: Q = p@wq, Ks = (p@wk)*SCALE, V = p@wv  (rows 0..2047), q1 = queries@cq_wq
// grid 2304 x 64
// ---------------------------------------------------------------------------
__global__ void k_proj(const float* __restrict__ p, const float* __restrict__ quer,
                       const float* __restrict__ wq, const float* __restrict__ wk,
                       const float* __restrict__ wv, const float* __restrict__ cq_wq,
                       float* __restrict__ Q, float* __restrict__ Ks,
                       float* __restrict__ V, float* __restrict__ q1) {
  int blk = blockIdx.x, t = threadIdx.x;
  __shared__ float xr[64];
  if (blk < 2048) {
    xr[t] = p[blk * 64 + t];
    __syncthreads();
    float aq = 0.f, ak = 0.f, av = 0.f;
    for (int c = 0; c < 64; c++) {
      float x = xr[c];
      aq += x * wq[c * 64 + t];
      ak += x * wk[c * 64 + t];
      av += x * wv[c * 64 + t];
    }
    Q[blk * 64 + t] = aq;
    Ks[blk * 64 + t] = ak * ATT_SCALE;
    V[blk * 64 + t] = av;
  } else {
    int r = blk - 2048;  // 0..255 query rows
    xr[t] = quer[r * 64 + t];
    __syncthreads();
    float a = 0.f;
    for (int c = 0; c < 64; c++) a += xr[c] * cq_wq[c * 64 + t];
    q1[r * 64 + t] = a;
  }
}

// ---------------------------------------------------------------------------
// K2 v3: edge attention, transposed MFMA (acc = mfma(wfrag, efrag) -> E^T).
// Parity-split V accumulation: after shfl_xor(s,16) quad-parities hold the
// same weight, so parity 0 accumulates dims 0..3, parity 1 dims 4..7.
// 1-deep software prefetch of the next e tile.
// grid 2048 x 256 (wave w owns j in [w*64, w*64+64))
// ---------------------------------------------------------------------------
__global__ __launch_bounds__(256) void k_edge(
    const float* __restrict__ e, const float* __restrict__ we,
    const float* __restrict__ krw, const float* __restrict__ mask,
    const float* __restrict__ hin, const float* __restrict__ pin,
    const float* __restrict__ wo, const float* __restrict__ cq_wkv,
    const float* __restrict__ Q, const float* __restrict__ Ks,
    const float* __restrict__ V, float* __restrict__ Kc, float* __restrict__ Vc) {
  int bi = blockIdx.x;          // b*256 + i
  int b = bi >> 8;
  int t = threadIdx.x;
  int w = t >> 6, l = t & 63;
  int l15 = l & 15, quad = l >> 4;
  int hsel = quad >> 1;         // head offset within an nt pair (0 or 1)
  int par = quad & 1;           // dim-half this lane accumulates

  // we fragments: lane holds we[c = kc*32+quad*8+jj][hk = nt*16+l15]
  bf16x8 wfrag[4][2];
  for (int nt = 0; nt < 4; nt++)
    for (int kc = 0; kc < 2; kc++)
      for (int jj = 0; jj < 8; jj++)
        wfrag[nt][kc][jj] = f2b(we[(kc * 32 + quad * 8 + jj) * 64 + nt * 16 + l15]);

  // Q fragments: qv[nt] = Q[i][nt*16 + quad*4 .. +3]
  float4 qv[4];
#pragma unroll
  for (int nt = 0; nt < 4; nt++)
    qv[nt] = *(const float4*)(Q + bi * 64 + nt * 16 + quad * 4);

  float mi = mask[bi];

  float aout[4][4];
  float aden[4] = {0.f, 0.f, 0.f, 0.f};
#pragma unroll
  for (int nt = 0; nt < 4; nt++)
#pragma unroll
    for (int d = 0; d < 4; d++) aout[nt][d] = 0.f;

  const float* ebase = e + ((long)bi * 256 + w * 64 + l15) * 64 + quad * 8;
  float4 c0 = *(const float4*)(ebase);
  float4 c1 = *(const float4*)(ebase + 4);
  float4 c2 = *(const float4*)(ebase + 32);
  float4 c3 = *(const float4*)(ebase + 36);

  for (int jt = 0; jt < 4; jt++) {
    float4 n0, n1, n2, n3;
    if (jt < 3) {
      const float* np = ebase + (jt + 1) * 1024;  // +16 rows of 64 floats
      n0 = *(const float4*)(np);
      n1 = *(const float4*)(np + 4);
      n2 = *(const float4*)(np + 32);
      n3 = *(const float4*)(np + 36);
    }
    int j = w * 64 + jt * 16 + l15;
    bf16x8 a0, a1;
    a0[0] = f2b(c0.x); a0[1] = f2b(c0.y); a0[2] = f2b(c0.z); a0[3] = f2b(c0.w);
    a0[4] = f2b(c1.x); a0[5] = f2b(c1.y); a0[6] = f2b(c1.z); a0[7] = f2b(c1.w);
    a1[0] = f2b(c2.x); a1[1] = f2b(c2.y); a1[2] = f2b(c2.z); a1[3] = f2b(c2.w);
    a1[4] = f2b(c3.x); a1[5] = f2b(c3.y); a1[6] = f2b(c3.z); a1[7] = f2b(c3.w);

    float kwm = krw[(long)bi * 256 + j] * mask[b * 256 + j];
    const float* ksrow = Ks + ((long)(b * 256 + j)) * 64 + quad * 4;
    const float* vrow = V + ((long)(b * 256 + j)) * 64 + hsel * 8 + par * 4;

#pragma unroll
    for (int nt = 0; nt < 4; nt++) {
      floatx4 acc = {0.f, 0.f, 0.f, 0.f};
      acc = __builtin_amdgcn_mfma_f32_16x16x32_bf16(wfrag[nt][0], a0, acc, 0, 0, 0);
      acc = __builtin_amdgcn_mfma_f32_16x16x32_bf16(wfrag[nt][1], a1, acc, 0, 0, 0);
      // acc[r] = E[hk = nt*16 + quad*4 + r][j]
      float4 kf = *(const float4*)(ksrow + nt * 16);
      float s = acc[0] * kf.x * qv[nt].x + acc[1] * kf.y * qv[nt].y +
                acc[2] * kf.z * qv[nt].z + acc[3] * kf.w * qv[nt].w;
      s += __shfl_xor(s, 16);   // quad pairs {0,1},{2,3}: full 8-k head sum
      float wg = __expf(s) * kwm;
      aden[nt] += wg;
      float4 va = *(const float4*)(vrow + nt * 16);
      aout[nt][0] += wg * va.x; aout[nt][1] += wg * va.y;
      aout[nt][2] += wg * va.z; aout[nt][3] += wg * va.w;
    }
    if (jt < 3) { c0 = n0; c1 = n1; c2 = n2; c3 = n3; }
  }

  // reduce over the 16 j's per lane-group (l15)
#pragma unroll
  for (int nt = 0; nt < 4; nt++) {
    float dn = aden[nt];
    dn += __shfl_xor(dn, 1); dn += __shfl_xor(dn, 2);
    dn += __shfl_xor(dn, 4); dn += __shfl_xor(dn, 8);
    aden[nt] = dn;
#pragma unroll
    for (int d = 0; d < 4; d++) {
      float o = aout[nt][d];
      o += __shfl_xor(o, 1); o += __shfl_xor(o, 2);
      o += __shfl_xor(o, 4); o += __shfl_xor(o, 8);
      aout[nt][d] = o;
    }
  }

  __shared__ float red[4][64];
  __shared__ float redden[4][8];
  __shared__ float pav[64];
  __shared__ float hcl[64];
  if (l15 == 0) {               // lanes 0,16,32,48 of each wave
#pragma unroll
    for (int nt = 0; nt < 4; nt++) {
      int head = nt * 2 + hsel;
#pragma unroll
      for (int d = 0; d < 4; d++) red[w][head * 8 + par * 4 + d] = aout[nt][d];
      if (par == 0) redden[w][head] = aden[nt];
    }
  }
  __syncthreads();
  if (t < 64) {
    int head = t >> 3;
    float num = red[0][t] + red[1][t] + red[2][t] + red[3][t];
    float den = redden[0][head] + redden[1][head] + redden[2][head] + redden[3][head];
    num *= mi;
    den = fmaxf(den * mi, 1e-6f);
    pav[t] = num / den;  // p_attn[b,i,head*8+d]
  }
  __syncthreads();
  if (t < 64) {
    float a = 0.f;
    for (int c = 0; c < 64; c++) a += pav[c] * wo[c * 64 + t];
    hcl[t] = hin[bi * 64 + t] + pin[bi * 64 + t] + tanhf(a);
  }
  __syncthreads();
  if (t < 128) {
    float a = 0.f;
    for (int c = 0; c < 64; c++) a += hcl[c] * cq_wkv[c * 128 + t];
    if (t < 64) Kc[bi * 64 + t] = a;
    else        Vc[bi * 64 + t - 64] = a;
  }
}

// ---------------------------------------------------------------------------
// KA: cross-attn (4 latent rows per block, all heads) + q0 = quer + oc@cq_wo
//     + bo, then qq/kv projections for self-attn layer 0.
// grid 64 (b*8+rg) x 256. Row-local LDS only -> no barriers needed.
// ---------------------------------------------------------------------------
__global__ __launch_bounds__(256) void k_crossf(
    const float* __restrict__ q1, const float* __restrict__ Kc,
    const float* __restrict__ Vc, const float* __restrict__ mask,
    const float* __restrict__ quer, const float* __restrict__ cq_wo,
    const float* __restrict__ cq_bo, const float* __restrict__ wq0,
    const float* __restrict__ wkv0, float* __restrict__ q0g,
    float* __restrict__ qqg, float* __restrict__ kvg) {
  int blk = blockIdx.x, b = blk >> 3, rg = blk & 7;
  int t = threadIdx.x, rr = t >> 6, l = t & 63, h = l >> 3, g = l & 7;
  int gr = b * 32 + rg * 4 + rr;  // global latent row
  __shared__ float ocs[4][64];
  __shared__ float q0s[4][64];

  {
    const float* qp = q1 + gr * 64 + h * 8;
    float4 qa = *(const float4*)qp, qb = *(const float4*)(qp + 4);
    float num[8] = {0.f, 0.f, 0.f, 0.f, 0.f, 0.f, 0.f, 0.f};
    float den = 0.f;
#pragma unroll 4
    for (int jj = 0; jj < 32; jj++) {
      int j = jj * 8 + g;
      const float* kp = Kc + (b * 256 + j) * 64 + h * 8;
      float4 ka = *(const float4*)kp, kb = *(const float4*)(kp + 4);
      float s = qa.x * ka.x + qa.y * ka.y + qa.z * ka.z + qa.w * ka.w +
                qb.x * kb.x + qb.y * kb.y + qb.z * kb.z + qb.w * kb.w;
      s *= ATT_SCALE;
      float mj = mask[b * 256 + j];
      s = (mj > 0.5f) ? s : -1e30f;
      s = fminf(fmaxf(s, -5.f), 5.f);
      float ex = __expf(s);
      den += ex;
      const float* vp = Vc + (b * 256 + j) * 64 + h * 8;
      float4 va = *(const float4*)vp, vb = *(const float4*)(vp + 4);
      num[0] += ex * va.x; num[1] += ex * va.y;
      num[2] += ex * va.z; num[3] += ex * va.w;
      num[4] += ex * vb.x; num[5] += ex * vb.y;
      num[6] += ex * vb.z; num[7] += ex * vb.w;
    }
    den += __shfl_xor(den, 1); den += __shfl_xor(den, 2); den += __shfl_xor(den, 4);
#pragma unroll
    for (int d = 0; d < 8; d++) {
      float v = num[d];
      v += __shfl_xor(v, 1); v += __shfl_xor(v, 2); v += __shfl_xor(v, 4);
      num[d] = v;
    }
    float sel = num[0];
#pragma unroll
    for (int d = 1; d < 8; d++) sel = (g == d) ? num[d] : sel;
    ocs[rr][h * 8 + g] = sel / den;   // row-local: read only by this wave
  }

  int c = l;
  {
    float acc = quer[gr * 64 + c] + cq_bo[c];
    for (int k = 0; k < 64; k++) acc += ocs[rr][k] * cq_wo[k * 64 + c];
    q0g[gr * 64 + c] = acc;
    q0s[rr][c] = acc;
  }
  {
    float aq = 0.f, ak = 0.f, av = 0.f;
    for (int k = 0; k < 64; k++) {
      float x = q0s[rr][k];
      aq += x * wq0[k * 64 + c];
      ak += x * wkv0[k * 128 + c];
      av += x * wkv0[k * 128 + 64 + c];
    }
    qqg[gr * 64 + c] = aq;
    kvg[gr * 128 + c] = ak;
    kvg[gr * 128 + 64 + c] = av;
  }
}

// ---------------------------------------------------------------------------
// KB: latent self-attn (4 rows per block, K/V staged in LDS) + residual
//     projection + next layer's qq/kv projections.
// grid 64 x 256, one barrier (after K/V stage).
// ---------------------------------------------------------------------------
__global__ __launch_bounds__(256) void k_sattnf(
    const float* __restrict__ qq, const float* __restrict__ kv,
    const float* __restrict__ resid, const float* __restrict__ wo,
    const float* __restrict__ bo, const float* __restrict__ wq2,
    const float* __restrict__ wkv2, float* __restrict__ q_out,
    float* __restrict__ qq2, float* __restrict__ kv2) {
  int blk = blockIdx.x, b = blk >> 3, rg = blk & 7;
  int t = threadIdx.x, rr = t >> 6, l = t & 63, h = l >> 3, g = l & 7;
  int gr = b * 32 + rg * 4 + rr;
  __shared__ float KVs[32][128];
  __shared__ float ocs[4][64];
  __shared__ float q2s[4][64];

  const float4* s4 = (const float4*)(kv + b * 4096);
  float4* d4 = (float4*)&KVs[0][0];
#pragma unroll
  for (int i = 0; i < 4; i++) d4[i * 256 + t] = s4[i * 256 + t];

  const float* qp = qq + gr * 64 + h * 8;
  float4 qa = *(const float4*)qp, qb = *(const float4*)(qp + 4);
  __syncthreads();

  {
    float num[8] = {0.f, 0.f, 0.f, 0.f, 0.f, 0.f, 0.f, 0.f};
    float den = 0.f;
#pragma unroll
    for (int jj = 0; jj < 4; jj++) {
      int j = jj * 8 + g;
      float4 ka = *(const float4*)&KVs[j][h * 8];
      float4 kb = *(const float4*)&KVs[j][h * 8 + 4];
      float s = qa.x * ka.x + qa.y * ka.y + qa.z * ka.z + qa.w * ka.w +
                qb.x * kb.x + qb.y * kb.y + qb.z * kb.z + qb.w * kb.w;
      s *= ATT_SCALE;
      s = fminf(fmaxf(s, -5.f), 5.f);
      float ex = __expf(s);
      den += ex;
      float4 va = *(const float4*)&KVs[j][64 + h * 8];
      float4 vb = *(const float4*)&KVs[j][64 + h * 8 + 4];
      num[0] += ex * va.x; num[1] += ex * va.y;
      num[2] += ex * va.z; num[3] += ex * va.w;
      num[4] += ex * vb.x; num[5] += ex * vb.y;
      num[6] += ex * vb.z; num[7] += ex * vb.w;
    }
    den += __shfl_xor(den, 1); den += __shfl_xor(den, 2); den += __shfl_xor(den, 4);
#pragma unroll
    for (int d = 0; d < 8; d++) {
      float v = num[d];
      v += __shfl_xor(v, 1); v += __shfl_xor(v, 2); v += __shfl_xor(v, 4);
      num[d] = v;
    }
    float sel = num[0];
#pragma unroll
    for (int d = 1; d < 8; d++) sel = (g == d) ? num[d] : sel;
    ocs[rr][h * 8 + g] = sel / den;
  }

  int c = l;
  {
    float acc = resid[gr * 64 + c] + bo[c];
    for (int k = 0; k < 64; k++) acc += ocs[rr][k] * wo[k * 64 + c];
    q_out[gr * 64 + c] = acc;
    q2s[rr][c] = acc;
  }
  {
    float aq = 0.f, ak = 0.f, av = 0.f;
    for (int k = 0; k < 64; k++) {
      float x = q2s[rr][k];
      aq += x * wq2[k * 64 + c];
      ak += x * wkv2[k * 128 + c];
      av += x * wkv2[k * 128 + 64 + c];
    }
    qq2[gr * 64 + c] = aq;
    kv2[gr * 128 + c] = ak;
    kv2[gr * 128 + 64 + c] = av;
  }
}

// ---------------------------------------------------------------------------
// KC: latent self-attn layer 1 + q2 residual + oq_w + LN1 + FFN + LN2 -> out
// grid 64 x 256, one barrier.
// ---------------------------------------------------------------------------
__global__ __launch_bounds__(256) void k_finalf(
    const float* __restrict__ qq, const float* __restrict__ kv,
    const float* __restrict__ resid, const float* __restrict__ wo,
    const float* __restrict__ bo, const float* __restrict__ oqw,
    const float* __restrict__ g1, const float* __restrict__ b1,
    const float* __restrict__ w1, const float* __restrict__ w2,
    const float* __restrict__ g2, const float* __restrict__ b2v,
    float* __restrict__ out) {
  int blk = blockIdx.x, b = blk >> 3, rg = blk & 7;
  int t = threadIdx.x, rr = t >> 6, l = t & 63, h = l >> 3, g = l & 7;
  int gr = b * 32 + rg * 4 + rr;
  __shared__ float KVs[32][128];
  __shared__ float ocs[4][64];
  __shared__ float xs[4][64];
  __shared__ float hs[4][128];

  const float4* s4 = (const float4*)(kv + b * 4096);
  float4* d4 = (float4*)&KVs[0][0];
#pragma unroll
  for (int i = 0; i < 4; i++) d4[i * 256 + t] = s4[i * 256 + t];

  const float* qp = qq + gr * 64 + h * 8;
  float4 qa = *(const float4*)qp, qb = *(const float4*)(qp + 4);
  __syncthreads();

  {
    float num[8] = {0.f, 0.f, 0.f, 0.f, 0.f, 0.f, 0.f, 0.f};
    float den = 0.f;
#pragma unroll
    for (int jj = 0; jj < 4; jj++) {
      int j = jj * 8 + g;
      float4 ka = *(const float4*)&KVs[j][h * 8];
      float4 kb = *(const float4*)&KVs[j][h * 8 + 4];
      float s = qa.x * ka.x + qa.y * ka.y + qa.z * ka.z + qa.w * ka.w +
                qb.x * kb.x + qb.y * kb.y + qb.z * kb.z + qb.w * kb.w;
      s *= ATT_SCALE;
      s = fminf(fmaxf(s, -5.f), 5.f);
      float ex = __expf(s);
      den += ex;
      float4 va = *(const float4*)&KVs[j][64 + h * 8];
      float4 vb = *(const float4*)&KVs[j][64 + h * 8 + 4];
      num[0] += ex * va.x; num[1] += ex * va.y;
      num[2] += ex * va.z; num[3] += ex * va.w;
      num[4] += ex * vb.x; num[5] += ex * vb.y;
      num[6] += ex * vb.z; num[7] += ex * vb.w;
    }
    den += __shfl_xor(den, 1); den += __shfl_xor(den, 2); den += __shfl_xor(den, 4);
#pragma unroll
    for (int d = 0; d < 8; d++) {
      float v = num[d];
      v += __shfl_xor(v, 1); v += __shfl_xor(v, 2); v += __shfl_xor(v, 4);
      num[d] = v;
    }
    float sel = num[0];
#pragma unroll
    for (int d = 1; d < 8; d++) sel = (g == d) ? num[d] : sel;
    ocs[rr][h * 8 + g] = sel / den;
  }

  int c = l;
  float y;
  {
    float acc = resid[gr * 64 + c] + bo[c];
    for (int k = 0; k < 64; k++) acc += ocs[rr][k] * wo[k * 64 + c];
    xs[rr][c] = acc;   // q2 (row-local)
  }
  {
    float x = 0.f;
    for (int k = 0; k < 64; k++) x += xs[rr][k] * oqw[k * 64 + c];
    float m = x;
    for (int off = 1; off < 64; off <<= 1) m += __shfl_xor(m, off);
    m *= (1.f / 64.f);
    float dv = x - m, vv = dv * dv;
    for (int off = 1; off < 64; off <<= 1) vv += __shfl_xor(vv, off);
    vv *= (1.f / 64.f);
    y = dv * rsqrtf(vv + 1e-5f) * g1[c] + b1[c];
    xs[rr][c] = y;     // reuse: this wave done reading q2
  }
  {
    float h1 = 0.f, h2 = 0.f;
    for (int k = 0; k < 64; k++) {
      float xx = xs[rr][k];
      h1 += xx * w1[k * 128 + c];
      h2 += xx * w1[k * 128 + 64 + c];
    }
    hs[rr][c] = fmaxf(h1, 0.f);
    hs[rr][64 + c] = fmaxf(h2, 0.f);
  }
  {
    float ff = 0.f;
    for (int k = 0; k < 128; k++) ff += hs[rr][k] * w2[k * 64 + c];
    float z = y + ff;
    float m2 = z;
    for (int off = 1; off < 64; off <<= 1) m2 += __shfl_xor(m2, off);
    m2 *= (1.f / 64.f);
    float dz = z - m2, v2 = dz * dz;
    for (int off = 1; off < 64; off <<= 1) v2 += __shfl_xor(v2, off);
    v2 *= (1.f / 64.f);
    out[gr * 64 + c] = dz * rsqrtf(v2 + 1e-5f) * g2[c] + b2v[c];
  }
}

// ---------------------------------------------------------------------------
extern "C" void kernel_launch(void* const* d_in, const int* in_sizes, int n_in,
                              void* d_out, int out_size, void* d_ws, size_t ws_size,
                              hipStream_t stream) {
  const float* h_in   = (const float*)d_in[0];
  const float* p_in   = (const float*)d_in[1];
  const float* e_in   = (const float*)d_in[2];
  const float* krw    = (const float*)d_in[3];
  const float* quer   = (const float*)d_in[4];
  const float* mask   = (const float*)d_in[5];
  const float* wq_p   = (const float*)d_in[6];
  const float* wk_p   = (const float*)d_in[7];
  const float* we_p   = (const float*)d_in[8];
  const float* wv_p   = (const float*)d_in[9];
  const float* wo_p   = (const float*)d_in[10];
  const float* cq_wq  = (const float*)d_in[11];
  const float* cq_wkv = (const float*)d_in[12];
  const float* cq_wo  = (const float*)d_in[13];
  const float* cq_bo  = (const float*)d_in[14];
  const float* sa_wq  = (const float*)d_in[15];
  const float* sa_wkv = (const float*)d_in[16];
  const float* sa_wo  = (const float*)d_in[17];
  const float* sa_bo  = (const float*)d_in[18];
  const float* oq_w   = (const float*)d_in[19];
  const float* ln1_g  = (const float*)d_in[20];
  const float* ln1_b  = (const float*)d_in[21];
  const float* ffn_w1 = (const float*)d_in[22];
  const float* ffn_w2 = (const float*)d_in[23];
  const float* ln2_g  = (const float*)d_in[24];
  const float* ln2_b  = (const float*)d_in[25];

  float* ws = (float*)d_ws;
  float* Q   = ws;              // 131072
  float* Ks  = Q + 131072;      // 131072
  float* V   = Ks + 131072;     // 131072
  float* q1  = V + 131072;      // 16384
  float* Kc  = q1 + 16384;      // 131072
  float* Vc  = Kc + 131072;     // 131072
  float* q0  = Vc + 131072;     // 16384
  float* qc1 = q0 + 16384;      // 16384
  float* qqA = qc1 + 16384;     // 16384
  float* qqB = qqA + 16384;     // 16384
  float* kvA = qqB + 16384;     // 32768
  float* kvB = kvA + 32768;     // 32768

  k_proj<<<2304, 64, 0, stream>>>(p_in, quer, wq_p, wk_p, wv_p, cq_wq, Q, Ks, V, q1);
  k_edge<<<2048, 256, 0, stream>>>(e_in, we_p, krw, mask, h_in, p_in, wo_p, cq_wkv,
                                   Q, Ks, V, Kc, Vc);
  k_crossf<<<64, 256, 0, stream>>>(q1, Kc, Vc, mask, quer, cq_wo, cq_bo,
                                   sa_wq, sa_wkv, q0, qqA, kvA);
  k_sattnf<<<64, 256, 0, stream>>>(qqA, kvA, q0, sa_wo, sa_bo,
                                   sa_wq + 4096, sa_wkv + 8192, qc1, qqB, kvB);
  k_finalf<<<64, 256, 0, stream>>>(qqB, kvB, qc1, sa_wo + 4096, sa_bo + 64, oq_w,
                                   ln1_g, ln1_b, ffn_w1, ffn_w2, ln2_g, ln2_b,
                                   (float*)d_out);
}